// Round 3
// baseline (653.810 us; speedup 1.0000x reference)
//
#include <hip/hip_runtime.h>

#define DEVI __device__ __forceinline__

typedef __attribute__((ext_vector_type(8))) __bf16 bf16x8;
typedef __attribute__((ext_vector_type(4))) float floatx4;

constexpr int Bsz = 8192;   // batch
constexpr int Hd  = 2048;   // hidden
constexpr int INd = 2048;   // input dim
constexpr int Kd  = 4096;   // IN + H
constexpr int N1  = Bsz * INd;

DEVI unsigned short f2bf_rne(float f) {
  unsigned int u = __float_as_uint(f);
  u += 0x7FFFu + ((u >> 16) & 1u);
  return (unsigned short)(u >> 16);
}

__global__ void cvt4(const float* __restrict__ s0, const float* __restrict__ s1,
                     const float* __restrict__ s2, const float* __restrict__ s3,
                     unsigned short* __restrict__ dst) {
  const float* src = (blockIdx.y == 0) ? s0 : (blockIdx.y == 1) ? s1
                   : (blockIdx.y == 2) ? s2 : s3;
  unsigned short* out = dst + (size_t)blockIdx.y * N1;
  const int nv = N1 / 4;
  for (int i = blockIdx.x * blockDim.x + threadIdx.x; i < nv;
       i += gridDim.x * blockDim.x) {
    float4 v = ((const float4*)src)[i];
    ushort4 o;
    o.x = f2bf_rne(v.x); o.y = f2bf_rne(v.y);
    o.z = f2bf_rne(v.z); o.w = f2bf_rne(v.w);
    ((ushort4*)out)[i] = o;
  }
}

DEVI void gload_lds16(const void* g, void* l) {
  __builtin_amdgcn_global_load_lds(
      (const __attribute__((address_space(1))) void*)g,
      (__attribute__((address_space(3))) void*)l, 16, 0, 0);
}

DEVI float sigm(float x) { return 1.0f / (1.0f + __expf(-x)); }

// 256x256 tile, BK=64, 8 waves (2M x 4N), 8-phase counted-vmcnt schedule.
// LDS: A[2buf][256][64] + B[2buf][256][64] bf16 = 128 KiB, chunk-XOR swizzled.
// Block cols = 4 gates x 64 h-cols; wave (wm,wn) owns rows {0,128}+wm*64+[0,64)
// x cols with cf = qn*8+wn*2+nc -> gate nc+2qn, h-chunk wn  (epilogue lane-local).
__global__ __launch_bounds__(512, 2) void lstm_gemm(
    const unsigned short* __restrict__ ws,
    const float* __restrict__ bias,
    const float* __restrict__ c_prev,
    float* __restrict__ out_h,
    float* __restrict__ out_c) {
  __shared__ __align__(16) unsigned short sm[4 * 256 * 64];  // 128 KiB
  char* smc = (char*)sm;

  const unsigned short* xb  = ws;
  const unsigned short* hb  = ws + (size_t)N1;
  const unsigned short* wih = ws + (size_t)2 * N1;
  const unsigned short* whh = ws + (size_t)3 * N1;

  const int tid  = threadIdx.x;
  const int lane = tid & 63;
  const int wid  = tid >> 6;
  const int wm   = wid >> 2, wn = wid & 3;
  const int lr   = lane & 15, lk = lane >> 4;
  const int lr8  = lane >> 3;
  const int swc  = ((lane & 7) ^ lr8) * 8;   // swizzled source chunk (elems)

  // XCD-aware swizzle over 1024 blocks (1024 % 8 == 0 -> bijective).
  const int wg  = blockIdx.x;
  const int swz = (wg & 7) * 128 + (wg >> 3);
  const int bc  = swz & 31;          // h-col tile (64 h-cols)
  const int rb  = (swz >> 5) * 256;  // batch row base

  // Precomputed per-thread stage source offsets (elements), tile-independent.
  unsigned int aOff[2][2], bOff[2][2];
#pragma unroll
  for (int h = 0; h < 2; ++h)
#pragma unroll
    for (int j = 0; j < 2; ++j) {
      const int arow = rb + h * 128 + j * 64 + wid * 8 + lr8;
      aOff[h][j] = (unsigned)arow * 2048u + (unsigned)swc;
      const int c  = h * 128 + j * 64 + wid * 8 + lr8;   // block-col index
      const int cf = c >> 4, ce = c & 15;
      const int gate = (cf & 1) | ((cf >> 2) & 2);
      const int hch  = (cf >> 1) & 3;
      const int brow = gate * 2048 + bc * 64 + hch * 16 + ce;
      bOff[h][j] = (unsigned)brow * 2048u + (unsigned)swc;
    }

  floatx4 acc[2][4][2][2];
#pragma unroll
  for (int a = 0; a < 2; ++a)
#pragma unroll
    for (int b = 0; b < 4; ++b)
#pragma unroll
      for (int c = 0; c < 2; ++c)
#pragma unroll
        for (int d = 0; d < 2; ++d)
          acc[a][b][c][d] = (floatx4){0.f, 0.f, 0.f, 0.f};

#define STAGE_A(ts, h) {                                                      \
    const int bs_ = (ts) & 1;                                                 \
    const unsigned short* s_ = (((ts) < 32) ? xb : hb) + (((ts) & 31) * 64);  \
    gload_lds16(s_ + aOff[h][0], smc + bs_ * 32768 + ((h) * 128 + wid * 8) * 128);        \
    gload_lds16(s_ + aOff[h][1], smc + bs_ * 32768 + ((h) * 128 + 64 + wid * 8) * 128); }
#define STAGE_B(ts, h) {                                                      \
    const int bs_ = (ts) & 1;                                                 \
    const unsigned short* s_ = (((ts) < 32) ? wih : whh) + (((ts) & 31) * 64);\
    gload_lds16(s_ + bOff[h][0], smc + 65536 + bs_ * 32768 + ((h) * 128 + wid * 8) * 128);        \
    gload_lds16(s_ + bOff[h][1], smc + 65536 + bs_ * 32768 + ((h) * 128 + 64 + wid * 8) * 128); }

#define PHASE(QM, QN, STAGES, WAITS) {                                        \
    const char* Abase = smc + beta * 32768;                                   \
    const char* Bbase = smc + 65536 + beta * 32768;                           \
    bf16x8 af[4][2], bg[2][2];                                                \
    _Pragma("unroll") for (int mr = 0; mr < 4; ++mr)                          \
      _Pragma("unroll") for (int s = 0; s < 2; ++s) {                         \
        const int row  = (QM) * 128 + wm * 64 + mr * 16 + lr;                 \
        const int phys = (s * 4 + lk) ^ (row & 7);                            \
        af[mr][s] = *(const bf16x8*)(Abase + row * 128 + phys * 16);          \
      }                                                                       \
    _Pragma("unroll") for (int nc = 0; nc < 2; ++nc)                          \
      _Pragma("unroll") for (int s = 0; s < 2; ++s) {                         \
        const int row  = ((QN) * 8 + wn * 2 + nc) * 16 + lr;                  \
        const int phys = (s * 4 + lk) ^ (row & 7);                            \
        bg[nc][s] = *(const bf16x8*)(Bbase + row * 128 + phys * 16);          \
      }                                                                       \
    STAGES;                                                                   \
    WAITS;                                                                    \
    asm volatile("s_barrier" ::: "memory");                                   \
    asm volatile("s_waitcnt lgkmcnt(0)" ::: "memory");                        \
    __builtin_amdgcn_sched_barrier(0);                                        \
    __builtin_amdgcn_s_setprio(1);                                            \
    _Pragma("unroll") for (int mr = 0; mr < 4; ++mr)                          \
      _Pragma("unroll") for (int nc = 0; nc < 2; ++nc)                        \
        _Pragma("unroll") for (int s = 0; s < 2; ++s)                         \
          acc[QM][mr][QN][nc] = __builtin_amdgcn_mfma_f32_16x16x32_bf16(      \
              af[mr][s], bg[nc][s], acc[QM][mr][QN][nc], 0, 0, 0);            \
    __builtin_amdgcn_s_setprio(0);                                            \
    asm volatile("s_barrier" ::: "memory");                                   \
  }

  // Prologue: stage in steady-state issue order, then counted drain.
  STAGE_B(0, 0); STAGE_A(0, 1); STAGE_B(0, 1);
  STAGE_A(0, 0); STAGE_B(1, 0); STAGE_A(1, 1);
  asm volatile("s_waitcnt vmcnt(4)" ::: "memory");
  asm volatile("s_barrier" ::: "memory");

  for (int t = 0; t < 62; ++t) {
    const int beta = t & 1;
    PHASE(0, 0, STAGE_B(t + 1, 1), );
    PHASE(1, 0, STAGE_A(t + 1, 0), );
    PHASE(1, 1, STAGE_B(t + 2, 0), );
    PHASE(0, 1, STAGE_A(t + 2, 1),
          asm volatile("s_waitcnt vmcnt(4)" ::: "memory"));
  }
  {  // t = 62: stage only tile 63's remaining halves; drain fully.
    const int beta = 0;
    PHASE(0, 0, STAGE_B(63, 1), );
    PHASE(1, 0, STAGE_A(63, 0), );
    PHASE(1, 1, , );
    PHASE(0, 1, , asm volatile("s_waitcnt vmcnt(0)" ::: "memory"));
  }
  {  // t = 63: compute only.
    const int beta = 1;
    PHASE(0, 0, , );
    PHASE(1, 0, , );
    PHASE(1, 1, , );
    PHASE(0, 1, , );
  }

  // Epilogue: lane-local LSTM (all 4 gates live in-lane).
  const int hcol = bc * 64 + wn * 16 + lr;
  const float b_i = bias[hcol];
  const float b_f = bias[2048 + hcol];
  const float b_j = bias[4096 + hcol];
  const float b_o = bias[6144 + hcol];
#pragma unroll
  for (int qm = 0; qm < 2; ++qm)
#pragma unroll
    for (int mr = 0; mr < 4; ++mr)
#pragma unroll
      for (int r = 0; r < 4; ++r) {
        const int row = rb + qm * 128 + wm * 64 + mr * 16 + lk * 4 + r;
        const float gi = acc[qm][mr][0][0][r] + b_i;
        const float gf = acc[qm][mr][0][1][r] + b_f;
        const float gj = acc[qm][mr][1][0][r] + b_j;
        const float go = acc[qm][mr][1][1][r] + b_o;
        const float iv = sigm(gi);
        const float fv = sigm(gf);
        const float jv = tanhf(gj);
        const float ov = sigm(go);
        const size_t idx = (size_t)row * 2048 + hcol;
        const float cp = c_prev[idx];
        const float cv = fv * cp + fminf(1.0f - fv, iv) * jv;
        out_h[idx] = ov * tanhf(cv);
        out_c[idx] = cv;
      }
}

extern "C" void kernel_launch(void* const* d_in, const int* in_sizes, int n_in,
                              void* d_out, int out_size, void* d_ws, size_t ws_size,
                              hipStream_t stream) {
  const float* x      = (const float*)d_in[0];
  const float* h_prev = (const float*)d_in[1];
  const float* c_prev = (const float*)d_in[2];
  const float* w_ih   = (const float*)d_in[3];
  const float* w_hh   = (const float*)d_in[4];
  const float* bias   = (const float*)d_in[5];

  float* out_h = (float*)d_out;
  float* out_c = out_h + (size_t)Bsz * Hd;
  unsigned short* wsb = (unsigned short*)d_ws;

  dim3 cgrid(2048, 4);
  cvt4<<<cgrid, 256, 0, stream>>>(x, h_prev, w_ih, w_hh, wsb);

  // 32 row-panels x 32 col-panels = 1024 blocks, 512 threads.
  lstm_gemm<<<1024, 512, 0, stream>>>(wsb, bias, c_prev, out_h, out_c);
}

// Round 4
// 599.764 us; speedup vs baseline: 1.0901x; 1.0901x over previous
//
#include <hip/hip_runtime.h>

#define DEVI __device__ __forceinline__

typedef __attribute__((ext_vector_type(8))) __bf16 bf16x8;
typedef __attribute__((ext_vector_type(4))) float floatx4;

constexpr int Bsz = 8192;   // batch
constexpr int Hd  = 2048;   // hidden
constexpr int INd = 2048;   // input dim
constexpr int N1  = Bsz * INd;

DEVI unsigned short f2bf_rne(float f) {
  unsigned int u = __float_as_uint(f);
  u += 0x7FFFu + ((u >> 16) & 1u);
  return (unsigned short)(u >> 16);
}

__global__ void cvt4(const float* __restrict__ s0, const float* __restrict__ s1,
                     const float* __restrict__ s2, const float* __restrict__ s3,
                     unsigned short* __restrict__ dst) {
  const float* src = (blockIdx.y == 0) ? s0 : (blockIdx.y == 1) ? s1
                   : (blockIdx.y == 2) ? s2 : s3;
  unsigned short* out = dst + (size_t)blockIdx.y * N1;
  const int nv = N1 / 4;
  for (int i = blockIdx.x * blockDim.x + threadIdx.x; i < nv;
       i += gridDim.x * blockDim.x) {
    float4 v = ((const float4*)src)[i];
    ushort4 o;
    o.x = f2bf_rne(v.x); o.y = f2bf_rne(v.y);
    o.z = f2bf_rne(v.z); o.w = f2bf_rne(v.w);
    ((ushort4*)out)[i] = o;
  }
}

DEVI void gload_lds16(const void* g, void* l) {
  __builtin_amdgcn_global_load_lds(
      (const __attribute__((address_space(1))) void*)g,
      (__attribute__((address_space(3))) void*)l, 16, 0, 0);
}

DEVI float sigm(float x) { return 1.0f / (1.0f + __expf(-x)); }

// 256x256 tile, BK=64, 8 waves (2M x 4N), 8-phase counted-vmcnt schedule with
// cross-phase fragment register reuse (B held over phase pairs, A1 over 2-3).
// ds_read_b128 per K-tile per wave: 32 (was 48) -> LDS-read no longer 2.4x MFMA.
__global__ __launch_bounds__(512, 2) void lstm_gemm(
    const unsigned short* __restrict__ ws,
    const float* __restrict__ bias,
    const float* __restrict__ c_prev,
    float* __restrict__ out_h,
    float* __restrict__ out_c) {
  __shared__ __align__(16) unsigned short sm[4 * 256 * 64];  // 128 KiB
  char* smc = (char*)sm;

  const unsigned short* xb  = ws;
  const unsigned short* hb  = ws + (size_t)N1;
  const unsigned short* wih = ws + (size_t)2 * N1;
  const unsigned short* whh = ws + (size_t)3 * N1;

  const int tid  = threadIdx.x;
  const int lane = tid & 63;
  const int wid  = tid >> 6;
  const int wm   = wid >> 2, wn = wid & 3;
  const int lr   = lane & 15, lk = lane >> 4;
  const int lr8  = lane >> 3;
  const int swc  = ((lane & 7) ^ lr8) * 8;   // swizzled source chunk (elems)

  // XCD-aware swizzle: XCD x gets a 16-row-panel x 8-col-panel chunk
  // (weights working set 16 MB + A 32 MB per XCD, vs 136 MB round-robin).
  const int wg = blockIdx.x;
  const int x8 = wg & 7;         // XCD (dispatch round-robin)
  const int lc = wg >> 3;        // 0..127 within XCD
  const int bc = (x8 & 3) * 8 + (lc & 7);          // h-col tile 0..31
  const int rb = ((x8 >> 2) * 16 + (lc >> 3)) * 256;  // batch row base

  // Per-thread stage source offsets (elements), tile-independent.
  unsigned int aOff[2][2], bOff[2][2];
#pragma unroll
  for (int h = 0; h < 2; ++h)
#pragma unroll
    for (int j = 0; j < 2; ++j) {
      const int arow = rb + h * 128 + j * 64 + wid * 8 + lr8;
      aOff[h][j] = (unsigned)arow * 2048u + (unsigned)swc;
      const int c  = h * 128 + j * 64 + wid * 8 + lr8;   // block-col index
      const int cf = c >> 4, ce = c & 15;
      const int gate = (cf & 1) | ((cf >> 2) & 2);
      const int hch  = (cf >> 1) & 3;
      const int brow = gate * 2048 + bc * 64 + hch * 16 + ce;
      bOff[h][j] = (unsigned)brow * 2048u + (unsigned)swc;
    }

  floatx4 acc[2][4][2][2];
#pragma unroll
  for (int a = 0; a < 2; ++a)
#pragma unroll
    for (int b = 0; b < 4; ++b)
#pragma unroll
      for (int c = 0; c < 2; ++c)
#pragma unroll
        for (int d = 0; d < 2; ++d)
          acc[a][b][c][d] = (floatx4){0.f, 0.f, 0.f, 0.f};

#define STAGE_A(ts, h) {                                                      \
    const int bs_ = (ts) & 1;                                                 \
    const unsigned short* s_ = (((ts) < 32) ? xb : hb) + (((ts) & 31) * 64);  \
    gload_lds16(s_ + aOff[h][0], smc + bs_ * 32768 + ((h) * 128 + wid * 8) * 128);        \
    gload_lds16(s_ + aOff[h][1], smc + bs_ * 32768 + ((h) * 128 + 64 + wid * 8) * 128); }
#define STAGE_B(ts, h) {                                                      \
    const int bs_ = (ts) & 1;                                                 \
    const unsigned short* s_ = (((ts) < 32) ? wih : whh) + (((ts) & 31) * 64);\
    gload_lds16(s_ + bOff[h][0], smc + 65536 + bs_ * 32768 + ((h) * 128 + wid * 8) * 128);        \
    gload_lds16(s_ + bOff[h][1], smc + 65536 + bs_ * 32768 + ((h) * 128 + 64 + wid * 8) * 128); }

#define LDA(DST, QM)                                                          \
  _Pragma("unroll") for (int mr = 0; mr < 4; ++mr)                            \
    _Pragma("unroll") for (int s = 0; s < 2; ++s) {                           \
      const int row  = (QM) * 128 + wm * 64 + mr * 16 + lr;                   \
      const int phys = (s * 4 + lk) ^ (row & 7);                              \
      DST[mr][s] = *(const bf16x8*)(Ab + row * 128 + phys * 16); }
#define LDB(DST, QN)                                                          \
  _Pragma("unroll") for (int nc = 0; nc < 2; ++nc)                            \
    _Pragma("unroll") for (int s = 0; s < 2; ++s) {                           \
      const int row  = ((QN) * 8 + wn * 2 + nc) * 16 + lr;                    \
      const int phys = (s * 4 + lk) ^ (row & 7);                              \
      DST[nc][s] = *(const bf16x8*)(Bb + row * 128 + phys * 16); }
#define MFMA16(QM, QN, AF, BG)                                                \
  __builtin_amdgcn_s_setprio(1);                                              \
  _Pragma("unroll") for (int mr = 0; mr < 4; ++mr)                            \
    _Pragma("unroll") for (int nc = 0; nc < 2; ++nc)                          \
      _Pragma("unroll") for (int s = 0; s < 2; ++s)                           \
        acc[QM][mr][QN][nc] = __builtin_amdgcn_mfma_f32_16x16x32_bf16(        \
            AF[mr][s], BG[nc][s], acc[QM][mr][QN][nc], 0, 0, 0);              \
  __builtin_amdgcn_s_setprio(0);
#define BAR  asm volatile("s_barrier" ::: "memory")
#define LGK0 do { asm volatile("s_waitcnt lgkmcnt(0)" ::: "memory");          \
                  __builtin_amdgcn_sched_barrier(0); } while (0)

// One K-tile = 4 phases. Fragment reuse: bg over {ph1,ph2} and {ph3,ph4},
// afB over {ph2,ph3}; afA re-read in ph4.
#define KTILE(BETA, S1, S2, S3, S4, W4) {                                     \
    const char* Ab = smc + (BETA) * 32768;                                    \
    const char* Bb = smc + 65536 + (BETA) * 32768;                            \
    bf16x8 afA[4][2], afB[4][2], bg[2][2];                                    \
    LDA(afA, 0); LDB(bg, 0); S1;                                              \
    asm volatile("s_waitcnt lgkmcnt(8)" ::: "memory");                        \
    BAR; LGK0; MFMA16(0, 0, afA, bg); BAR;                                    \
    LDA(afB, 1); S2;                                                          \
    BAR; LGK0; MFMA16(1, 0, afB, bg); BAR;                                    \
    LDB(bg, 1); S3;                                                           \
    BAR; LGK0; MFMA16(1, 1, afB, bg); BAR;                                    \
    LDA(afA, 0); S4; W4;                                                      \
    BAR; LGK0; MFMA16(0, 1, afA, bg); BAR;                                    \
  }
#define VM4  asm volatile("s_waitcnt vmcnt(4)" ::: "memory")
#define VM0  asm volatile("s_waitcnt vmcnt(0)" ::: "memory")
#define NOP  (void)0

  // Prologue: tile 0 complete + first halves of tile 1; counted drain.
  STAGE_B(0, 0); STAGE_A(0, 1); STAGE_B(0, 1);
  STAGE_A(0, 0); STAGE_B(1, 0); STAGE_A(1, 1);
  VM4;
  BAR;

  for (int t = 0; t < 62; ++t) {
    KTILE(t & 1, STAGE_B(t + 1, 1), STAGE_A(t + 1, 0),
          STAGE_B(t + 2, 0), STAGE_A(t + 2, 1), VM4);
  }
  KTILE(0, STAGE_B(63, 1), STAGE_A(63, 0), NOP, NOP, VM0);  // t = 62
  KTILE(1, NOP, NOP, NOP, NOP, NOP);                        // t = 63

  // Epilogue: lane-local LSTM (all 4 gates live in-lane).
  const int hcol = bc * 64 + wn * 16 + lr;
  const float b_i = bias[hcol];
  const float b_f = bias[2048 + hcol];
  const float b_j = bias[4096 + hcol];
  const float b_o = bias[6144 + hcol];
#pragma unroll
  for (int qm = 0; qm < 2; ++qm)
#pragma unroll
    for (int mr = 0; mr < 4; ++mr)
#pragma unroll
      for (int r = 0; r < 4; ++r) {
        const int row = rb + qm * 128 + wm * 64 + mr * 16 + lk * 4 + r;
        const float gi = acc[qm][mr][0][0][r] + b_i;
        const float gf = acc[qm][mr][0][1][r] + b_f;
        const float gj = acc[qm][mr][1][0][r] + b_j;
        const float go = acc[qm][mr][1][1][r] + b_o;
        const float iv = sigm(gi);
        const float fv = sigm(gf);
        const float jv = tanhf(gj);
        const float ov = sigm(go);
        const size_t idx = (size_t)row * 2048 + hcol;
        const float cp = c_prev[idx];
        const float cv = fv * cp + fminf(1.0f - fv, iv) * jv;
        out_h[idx] = ov * tanhf(cv);
        out_c[idx] = cv;
      }
}

extern "C" void kernel_launch(void* const* d_in, const int* in_sizes, int n_in,
                              void* d_out, int out_size, void* d_ws, size_t ws_size,
                              hipStream_t stream) {
  const float* x      = (const float*)d_in[0];
  const float* h_prev = (const float*)d_in[1];
  const float* c_prev = (const float*)d_in[2];
  const float* w_ih   = (const float*)d_in[3];
  const float* w_hh   = (const float*)d_in[4];
  const float* bias   = (const float*)d_in[5];

  float* out_h = (float*)d_out;
  float* out_c = out_h + (size_t)Bsz * Hd;
  unsigned short* wsb = (unsigned short*)d_ws;

  dim3 cgrid(2048, 4);
  cvt4<<<cgrid, 256, 0, stream>>>(x, h_prev, w_ih, w_hh, wsb);

  lstm_gemm<<<1024, 512, 0, stream>>>(wsb, bias, c_prev, out_h, out_c);
}